// Round 2
// baseline (129.784 us; speedup 1.0000x reference)
//
#include <hip/hip_runtime.h>
#include <cmath>

// Problem constants (fixed by setup_inputs)
#define BB 32
#define EE 256
#define NC 1024
#define NF 4096
#define TOKSTRIDE 5120   // Nc+Nf rows per batch
#define IMG 256

// ---------------- K1: coarse GEMM -> coarse image (pre-conv) ----------------
// tokens[:, :1024] @ W_coarse (256x64) + b_coarse, scattered into (B,256,256)
__global__ __launch_bounds__(256) void k_coarse(const float* __restrict__ tokens,
                                                const float* __restrict__ Wc,
                                                const float* __restrict__ bc,
                                                float* __restrict__ coarse_img) {
    __shared__ float tok[32][260];   // 260 pad: rows 16B-aligned
    const int tid = threadIdx.x;
    const int tokbase = blockIdx.x * 32;       // global coarse-token index (B*1024 total)
    const int b  = tokbase >> 10;
    const int t0 = tokbase & 1023;
    const float* src = tokens + ((size_t)b * TOKSTRIDE + t0) * EE;

    // stage 32 rows x 256 floats (32 KB), coalesced float4
    #pragma unroll
    for (int i = 0; i < 8; ++i) {
        int f = i * 1024 + tid * 4;            // flat float idx into 32x256 tile
        int r = f >> 8, c = f & 255;
        float4 v = *reinterpret_cast<const float4*>(src + f);
        *reinterpret_cast<float4*>(&tok[r][c]) = v;
    }
    __syncthreads();

    const int wave = tid >> 6;
    const int lane = tid & 63;                 // output column 0..63
    float acc[8] = {0.f,0.f,0.f,0.f,0.f,0.f,0.f,0.f};

    for (int k = 0; k < 256; k += 4) {
        float w0 = Wc[(k+0)*64 + lane];
        float w1 = Wc[(k+1)*64 + lane];
        float w2 = Wc[(k+2)*64 + lane];
        float w3 = Wc[(k+3)*64 + lane];
        #pragma unroll
        for (int t = 0; t < 8; ++t) {
            const float* tp = &tok[wave*8 + t][k];   // broadcast read (wave-uniform)
            float4 t4 = *reinterpret_cast<const float4*>(tp);
            acc[t] = fmaf(t4.x, w0, acc[t]);
            acc[t] = fmaf(t4.y, w1, acc[t]);
            acc[t] = fmaf(t4.z, w2, acc[t]);
            acc[t] = fmaf(t4.w, w3, acc[t]);
        }
    }

    const float bias = bc[lane];
    const int ph = lane >> 3, pw = lane & 7;
    #pragma unroll
    for (int t = 0; t < 8; ++t) {
        int tg = t0 + wave*8 + t;
        int hc = tg >> 5, wc = tg & 31;
        int h = hc*8 + ph, w = wc*8 + pw;
        coarse_img[(size_t)b*65536 + h*256 + w] = acc[t] + bias;
    }
}

// ---------------- K2: per-batch inclusive cumsum of mask ----------------
__global__ __launch_bounds__(256) void k_scan(const int* __restrict__ mask,
                                              int* __restrict__ cum) {
    __shared__ int sums[256];
    const int b = blockIdx.x;
    const int tid = threadIdx.x;
    const int* m = mask + b * NF;

    int loc[16];
    int s = 0;
    #pragma unroll
    for (int i = 0; i < 16; ++i) { int v = (m[tid*16 + i] != 0) ? 1 : 0; s += v; loc[i] = s; }
    sums[tid] = s;
    __syncthreads();

    // Hillis-Steele inclusive scan over 256 partial sums
    for (int off = 1; off < 256; off <<= 1) {
        int v = sums[tid];
        int add = (tid >= off) ? sums[tid - off] : 0;
        __syncthreads();
        sums[tid] = v + add;
        __syncthreads();
    }
    int excl = sums[tid] - s;
    #pragma unroll
    for (int i = 0; i < 16; ++i) cum[b*NF + tid*16 + i] = excl + loc[i];
}

// ---------------- K3: fine gather-GEMM -> fine image ----------------
// masked position j uses token row (1024 + cum[j]-1); unmasked -> zeros
__global__ __launch_bounds__(256) void k_fine(const float* __restrict__ tokens,
                                              const int* __restrict__ mask,
                                              const int* __restrict__ cum,
                                              const float* __restrict__ Wf,
                                              const float* __restrict__ bf,
                                              float* __restrict__ fine_map) {
    __shared__ float tok[64][260];
    const int tid = threadIdx.x;
    const int posbase = blockIdx.x * 64;       // global position over B*4096
    const int b  = posbase >> 12;
    const int j0 = posbase & 4095;             // multiple of 64 -> one hf row

    // stage masked rows: 16 iters x 4 rows; 64 threads per row (float4 each)
    const int lane64 = tid & 63;
    const int rgrp = tid >> 6;
    for (int it = 0; it < 16; ++it) {
        int rl = it*4 + rgrp;
        int j = j0 + rl;
        if (mask[b*NF + j] != 0) {
            int row = cum[b*NF + j] - 1;
            const float* src = tokens + ((size_t)b*TOKSTRIDE + NC + row) * EE;
            float4 v = *reinterpret_cast<const float4*>(src + lane64*4);
            *reinterpret_cast<float4*>(&tok[rl][lane64*4]) = v;
        }
    }
    __syncthreads();

    const int wave = tid >> 6;                 // column group: cols 4*wave..+3
    const int pos  = tid & 63;
    const int j = j0 + pos;
    const bool msk = (mask[b*NF + j] != 0);
    const int hf = j >> 6, wf = j & 63;
    const int c0 = wave * 4;
    const int h = hf*4 + wave;                 // ph = c0/4 = wave

    float4 outv;
    if (msk) {
        float a0=0.f, a1=0.f, a2=0.f, a3=0.f;
        for (int k = 0; k < 256; k += 4) {
            float4 t4 = *reinterpret_cast<const float4*>(&tok[pos][k]);
            float4 w0 = *reinterpret_cast<const float4*>(Wf + (k+0)*16 + c0);
            float4 w1 = *reinterpret_cast<const float4*>(Wf + (k+1)*16 + c0);
            float4 w2 = *reinterpret_cast<const float4*>(Wf + (k+2)*16 + c0);
            float4 w3 = *reinterpret_cast<const float4*>(Wf + (k+3)*16 + c0);
            a0 = fmaf(t4.x, w0.x, a0); a0 = fmaf(t4.y, w1.x, a0); a0 = fmaf(t4.z, w2.x, a0); a0 = fmaf(t4.w, w3.x, a0);
            a1 = fmaf(t4.x, w0.y, a1); a1 = fmaf(t4.y, w1.y, a1); a1 = fmaf(t4.z, w2.y, a1); a1 = fmaf(t4.w, w3.y, a1);
            a2 = fmaf(t4.x, w0.z, a2); a2 = fmaf(t4.y, w1.z, a2); a2 = fmaf(t4.z, w2.z, a2); a2 = fmaf(t4.w, w3.z, a2);
            a3 = fmaf(t4.x, w0.w, a3); a3 = fmaf(t4.y, w1.w, a3); a3 = fmaf(t4.z, w2.w, a3); a3 = fmaf(t4.w, w3.w, a3);
        }
        outv = make_float4(a0 + bf[c0], a1 + bf[c0+1], a2 + bf[c0+2], a3 + bf[c0+3]);
    } else {
        outv = make_float4(0.f, 0.f, 0.f, 0.f);
    }
    // pixel (h, wf*4 .. wf*4+3) -- coalesced float4 store across the wave
    *reinterpret_cast<float4*>(&fine_map[(size_t)b*65536 + h*256 + wf*4]) = outv;
}

// ---------------- K4: conv + blend + bilinear downsample ----------------
struct InterpArgs { int i0[32]; int i1[32]; float fr[32]; };

__global__ __launch_bounds__(256) void k_out(const float* __restrict__ coarse_img,
                                             const float* __restrict__ fine_map,
                                             const float* __restrict__ noise,
                                             const float* __restrict__ convw,
                                             float* __restrict__ out,
                                             InterpArgs ia) {
    const int tid = blockIdx.x * 256 + threadIdx.x;   // 32768
    const int b = tid >> 10;
    const int p = (tid >> 5) & 31;
    const int q = tid & 31;

    float kk[9];
    #pragma unroll
    for (int i = 0; i < 9; ++i) kk[i] = convw[i];

    const int   hs[2] = { ia.i0[p], ia.i1[p] };
    const float fh    = ia.fr[p];
    const float wh[2] = { 1.f - fh, fh };
    const int   wsx[2] = { ia.i0[q], ia.i1[q] };
    const float fw    = ia.fr[q];
    const float ww[2] = { 1.f - fw, fw };

    const float* cimg = coarse_img + (size_t)b*65536;
    const float* fimg = fine_map  + (size_t)b*65536;
    const float* nimg = noise     + (size_t)b*65536;

    float acc = 0.f;
    #pragma unroll
    for (int a = 0; a < 2; ++a) {
        #pragma unroll
        for (int c = 0; c < 2; ++c) {
            const int h = hs[a], w = wsx[c];
            float conv = 0.f;
            #pragma unroll
            for (int dh = -1; dh <= 1; ++dh) {
                #pragma unroll
                for (int dw = -1; dw <= 1; ++dw) {
                    int hh = h + dh, wp = w + dw;
                    float v = (hh >= 0 && hh < IMG && wp >= 0 && wp < IMG)
                              ? cimg[hh*IMG + wp] : 0.f;
                    conv = fmaf(v, kk[(dh+1)*3 + (dw+1)], conv);
                }
            }
            float s = 1.f / (1.f + expf(-0.1f * nimg[h*IMG + w]));
            float fv = fimg[h*IMG + w];
            acc += wh[a] * ww[c] * (conv * (1.f - s) + fv * s);
        }
    }
    out[tid] = acc;
}

extern "C" void kernel_launch(void* const* d_in, const int* in_sizes, int n_in,
                              void* d_out, int out_size, void* d_ws, size_t ws_size,
                              hipStream_t stream) {
    const float* tokens = (const float*)d_in[0];
    const int*   mask   = (const int*)  d_in[1];
    const float* Wc     = (const float*)d_in[2];
    const float* bc     = (const float*)d_in[3];
    const float* Wf     = (const float*)d_in[4];
    const float* bf     = (const float*)d_in[5];
    const float* convw  = (const float*)d_in[6];
    const float* noise  = (const float*)d_in[7];

    float* ws = (float*)d_ws;
    float* coarse_img = ws;                       // 32*65536 floats
    float* fine_map   = ws + (size_t)BB*65536;    // 32*65536 floats
    int*   cum        = (int*)(ws + (size_t)2*BB*65536);  // 32*4096 ints

    k_coarse<<<1024, 256, 0, stream>>>(tokens, Wc, bc, coarse_img);
    k_scan  <<<32,   256, 0, stream>>>(mask, cum);
    k_fine  <<<2048, 256, 0, stream>>>(tokens, mask, cum, Wf, bf, fine_map);

    InterpArgs ia;
    for (int p = 0; p < 32; ++p) {
        double pos = (double)p * 255.0 / 31.0;
        int i0 = (int)floor(pos);
        int i1 = (i0 + 1 < 256) ? i0 + 1 : 255;
        ia.i0[p] = i0; ia.i1[p] = i1; ia.fr[p] = (float)(pos - (double)i0);
    }
    k_out<<<128, 256, 0, stream>>>(coarse_img, fine_map, noise, convw, (float*)d_out, ia);
}

// Round 3
// 59.143 us; speedup vs baseline: 2.1944x; 2.1944x over previous
//
#include <hip/hip_runtime.h>
#include <cmath>

// Problem constants (fixed by setup_inputs)
#define BB 32
#define EE 256
#define NC 1024
#define NF 4096
#define TOKSTRIDE 5120   // Nc+Nf rows per batch
#define IMG 256

// ---------------- K1: coarse GEMM -> coarse image (pre-conv) ----------------
__global__ __launch_bounds__(256) void k_coarse(const float* __restrict__ tokens,
                                                const float* __restrict__ Wc,
                                                const float* __restrict__ bc,
                                                float* __restrict__ coarse_img) {
    __shared__ float tok[32][260];
    const int tid = threadIdx.x;
    const int tokbase = blockIdx.x * 32;
    const int b  = tokbase >> 10;
    const int t0 = tokbase & 1023;
    const float* src = tokens + ((size_t)b * TOKSTRIDE + t0) * EE;

    #pragma unroll
    for (int i = 0; i < 8; ++i) {
        int f = i * 1024 + tid * 4;
        int r = f >> 8, c = f & 255;
        float4 v = *reinterpret_cast<const float4*>(src + f);
        *reinterpret_cast<float4*>(&tok[r][c]) = v;
    }
    __syncthreads();

    const int wave = tid >> 6;
    const int lane = tid & 63;
    float acc[8] = {0.f,0.f,0.f,0.f,0.f,0.f,0.f,0.f};

    for (int k = 0; k < 256; k += 4) {
        float w0 = Wc[(k+0)*64 + lane];
        float w1 = Wc[(k+1)*64 + lane];
        float w2 = Wc[(k+2)*64 + lane];
        float w3 = Wc[(k+3)*64 + lane];
        #pragma unroll
        for (int t = 0; t < 8; ++t) {
            const float* tp = &tok[wave*8 + t][k];
            float4 t4 = *reinterpret_cast<const float4*>(tp);
            acc[t] = fmaf(t4.x, w0, acc[t]);
            acc[t] = fmaf(t4.y, w1, acc[t]);
            acc[t] = fmaf(t4.z, w2, acc[t]);
            acc[t] = fmaf(t4.w, w3, acc[t]);
        }
    }

    const float bias = bc[lane];
    const int ph = lane >> 3, pw = lane & 7;
    #pragma unroll
    for (int t = 0; t < 8; ++t) {
        int tg = t0 + wave*8 + t;
        int hc = tg >> 5, wc = tg & 31;
        int h = hc*8 + ph, w = wc*8 + pw;
        coarse_img[(size_t)b*65536 + h*256 + w] = acc[t] + bias;
    }
}

// ---------------- K2: per-batch inclusive cumsum of mask ----------------
__global__ __launch_bounds__(256) void k_scan(const int* __restrict__ mask,
                                              int* __restrict__ cum) {
    __shared__ int sums[256];
    const int b = blockIdx.x;
    const int tid = threadIdx.x;
    const int* m = mask + b * NF;

    int loc[16];
    int s = 0;
    #pragma unroll
    for (int i = 0; i < 16; ++i) { int v = (m[tid*16 + i] != 0) ? 1 : 0; s += v; loc[i] = s; }
    sums[tid] = s;
    __syncthreads();

    for (int off = 1; off < 256; off <<= 1) {
        int v = sums[tid];
        int add = (tid >= off) ? sums[tid - off] : 0;
        __syncthreads();
        sums[tid] = v + add;
        __syncthreads();
    }
    int excl = sums[tid] - s;
    #pragma unroll
    for (int i = 0; i < 16; ++i) cum[b*NF + tid*16 + i] = excl + loc[i];
}

// ---------------- K3: dense fine GEMM over compacted rows ----------------
// patch[b][row][16] = fine_tokens[b][row] @ Wf + bf, rows < cnt[b] meaningful.
// rank compaction: consecutive masked positions map to consecutive rows, so
// this is a pure streaming GEMM; scatter is fused into k_out.
__global__ __launch_bounds__(256) void k_gemm(const float* __restrict__ tokens,
                                              const int* __restrict__ cum,
                                              const float* __restrict__ Wf,
                                              const float* __restrict__ bf,
                                              float* __restrict__ patch) {
    const int b  = blockIdx.x >> 7;            // 128 tiles/batch
    const int r0 = (blockIdx.x & 127) * 32;
    const int cnt = cum[b*NF + NF - 1];
    if (r0 >= cnt) return;

    __shared__ float X[32][260];               // 33,280 B
    __shared__ float Wl[256*16];               // 16,384 B  (total 49,664 -> 3 blk/CU)
    const int tid = threadIdx.x;

    #pragma unroll
    for (int i = 0; i < 4; ++i) {
        int f = i*1024 + tid*4;
        *reinterpret_cast<float4*>(&Wl[f]) = *reinterpret_cast<const float4*>(Wf + f);
    }
    const float* src = tokens + ((size_t)b*TOKSTRIDE + NC + r0) * EE;
    #pragma unroll
    for (int i = 0; i < 8; ++i) {
        int f = i*1024 + tid*4;
        int r = f >> 8, c = f & 255;
        *reinterpret_cast<float4*>(&X[r][c]) = *reinterpret_cast<const float4*>(src + f);
    }
    __syncthreads();

    const int row = tid & 31;
    const int kh  = (tid >> 5) & 1;            // K half: 0 -> k<128, 1 -> k>=128
    const int cg  = tid >> 6;                  // column group 0..3
    const int c0  = cg * 4;
    const int kb  = kh * 128;

    float a0=0.f, a1=0.f, a2=0.f, a3=0.f;
    #pragma unroll 8
    for (int k = kb; k < kb + 128; k += 4) {
        float4 x  = *reinterpret_cast<const float4*>(&X[row][k]);
        float4 w0 = *reinterpret_cast<const float4*>(&Wl[(k+0)*16 + c0]);
        float4 w1 = *reinterpret_cast<const float4*>(&Wl[(k+1)*16 + c0]);
        float4 w2 = *reinterpret_cast<const float4*>(&Wl[(k+2)*16 + c0]);
        float4 w3 = *reinterpret_cast<const float4*>(&Wl[(k+3)*16 + c0]);
        a0 = fmaf(x.x,w0.x,a0); a0 = fmaf(x.y,w1.x,a0); a0 = fmaf(x.z,w2.x,a0); a0 = fmaf(x.w,w3.x,a0);
        a1 = fmaf(x.x,w0.y,a1); a1 = fmaf(x.y,w1.y,a1); a1 = fmaf(x.z,w2.y,a1); a1 = fmaf(x.w,w3.y,a1);
        a2 = fmaf(x.x,w0.z,a2); a2 = fmaf(x.y,w1.z,a2); a2 = fmaf(x.z,w2.z,a2); a2 = fmaf(x.w,w3.z,a2);
        a3 = fmaf(x.x,w0.w,a3); a3 = fmaf(x.y,w1.w,a3); a3 = fmaf(x.z,w2.w,a3); a3 = fmaf(x.w,w3.w,a3);
    }
    // combine the two K halves (partner lane differs only in bit 5)
    a0 += __shfl_xor(a0, 32, 64);
    a1 += __shfl_xor(a1, 32, 64);
    a2 += __shfl_xor(a2, 32, 64);
    a3 += __shfl_xor(a3, 32, 64);

    if (kh == 0) {
        float4 o = make_float4(a0 + bf[c0], a1 + bf[c0+1], a2 + bf[c0+2], a3 + bf[c0+3]);
        *reinterpret_cast<float4*>(&patch[((size_t)b*NF + r0 + row)*16 + c0]) = o;
    }
}

// ---------------- K4: fused scatter + conv + blend + downsample ----------------
struct InterpArgs { int i0[32]; int i1[32]; float fr[32]; };

__global__ __launch_bounds__(256) void k_out(const float* __restrict__ coarse_img,
                                             const float* __restrict__ patch,
                                             const int* __restrict__ mask,
                                             const int* __restrict__ cum,
                                             const float* __restrict__ noise,
                                             const float* __restrict__ convw,
                                             float* __restrict__ out,
                                             InterpArgs ia) {
    const int tid = blockIdx.x * 256 + threadIdx.x;   // 32768
    const int b = tid >> 10;
    const int p = (tid >> 5) & 31;
    const int q = tid & 31;

    float kk[9];
    #pragma unroll
    for (int i = 0; i < 9; ++i) kk[i] = convw[i];

    const int   hs[2]  = { ia.i0[p], ia.i1[p] };
    const float fh     = ia.fr[p];
    const float wh[2]  = { 1.f - fh, fh };
    const int   wsx[2] = { ia.i0[q], ia.i1[q] };
    const float fw     = ia.fr[q];
    const float ww[2]  = { 1.f - fw, fw };

    const float* cimg = coarse_img + (size_t)b*65536;
    const float* nimg = noise      + (size_t)b*65536;

    float acc = 0.f;
    #pragma unroll
    for (int a = 0; a < 2; ++a) {
        #pragma unroll
        for (int c = 0; c < 2; ++c) {
            const int h = hs[a], w = wsx[c];
            float conv = 0.f;
            #pragma unroll
            for (int dh = -1; dh <= 1; ++dh) {
                #pragma unroll
                for (int dw = -1; dw <= 1; ++dw) {
                    int hh = h + dh, wp = w + dw;
                    float v = (hh >= 0 && hh < IMG && wp >= 0 && wp < IMG)
                              ? cimg[hh*IMG + wp] : 0.f;
                    conv = fmaf(v, kk[(dh+1)*3 + (dw+1)], conv);
                }
            }
            // fine value via fused scatter: position j, sub-pixel column
            const int j = (h >> 2) * 64 + (w >> 2);
            float fv = 0.f;
            if (mask[b*NF + j] != 0) {
                int rk  = cum[b*NF + j] - 1;
                int col = (h & 3) * 4 + (w & 3);
                fv = patch[((size_t)b*NF + rk)*16 + col];
            }
            float s = 1.f / (1.f + expf(-0.1f * nimg[h*IMG + w]));
            acc += wh[a] * ww[c] * (conv * (1.f - s) + fv * s);
        }
    }
    out[tid] = acc;
}

extern "C" void kernel_launch(void* const* d_in, const int* in_sizes, int n_in,
                              void* d_out, int out_size, void* d_ws, size_t ws_size,
                              hipStream_t stream) {
    const float* tokens = (const float*)d_in[0];
    const int*   mask   = (const int*)  d_in[1];
    const float* Wc     = (const float*)d_in[2];
    const float* bc     = (const float*)d_in[3];
    const float* Wf     = (const float*)d_in[4];
    const float* bf     = (const float*)d_in[5];
    const float* convw  = (const float*)d_in[6];
    const float* noise  = (const float*)d_in[7];

    float* ws = (float*)d_ws;
    float* coarse_img = ws;                               // 32*65536 floats
    float* patch      = ws + (size_t)BB*65536;            // 32*4096*16 floats
    int*   cum        = (int*)(ws + (size_t)2*BB*65536);  // 32*4096 ints

    k_coarse<<<1024, 256, 0, stream>>>(tokens, Wc, bc, coarse_img);
    k_scan  <<<32,   256, 0, stream>>>(mask, cum);
    k_gemm  <<<4096, 256, 0, stream>>>(tokens, cum, Wf, bf, patch);

    InterpArgs ia;
    for (int p = 0; p < 32; ++p) {
        double pos = (double)p * 255.0 / 31.0;
        int i0 = (int)floor(pos);
        int i1 = (i0 + 1 < 256) ? i0 + 1 : 255;
        ia.i0[p] = i0; ia.i1[p] = i1; ia.fr[p] = (float)(pos - (double)i0);
    }
    k_out<<<128, 256, 0, stream>>>(coarse_img, patch, mask, cum, noise, convw,
                                   (float*)d_out, ia);
}